// Round 12
// baseline (521.064 us; speedup 1.0000x reference)
//
#include <hip/hip_runtime.h>

// GRUModel: 2-layer GRU (H=64), B=4096, T=512, fp32 in/out — MFMA round 12.
//
// R12 = R11 (470us) with ZERO-TRANS gate math. Empirical law from R8/R11:
//   window_cyc = 1361 + 32 * (trans instrs per SIMD)   [R8: 48 -> 2873 meas,
//   R11: 24 -> 2129 meas]. Also: marginal full-rate VALU hides in the fixed
//   envelope (R11's +256 Newton cyc cost nothing). So: replace the 3 v_exp
//   per cell with software exp2 (rndne + Horner-5 + v_ldexp, ~10 full-rate
//   instr, rel err 2.5e-6); rcp via magic seed + 2 Newton (rel 6e-6).
//   -> 0 trans instructions in the whole time loop.
//
// Structure (R8/R11): 256 blocks x 512 threads; waves 0-3 layer 0 @ window k,
// waves 4-7 layer 1 @ k-1; single fp16 MFMA operands; one barrier/window;
// parity double-buffered h planes; h-state fp32 in registers.
//
// Merged GRU cell (algebraically exact vs reference):
//   A=e^-az, B=e^-2w, C=e^-ar, w=ni+nh/(1+C),
//   h' = [A(1-B) + h(1+B)] / [(1+A)(1+B)]
//
// Frag layouts (m89/m120-verified):
//   A: lane holds A[m=lane&15][k=(lane>>4)*8+j], j=0..7
//   B: lane holds B[k=(lane>>4)*8+j][n=lane&15]
//   C/D: lane holds D[m=(lane>>4)*4+reg][n=lane&15]

typedef _Float16 half8 __attribute__((ext_vector_type(8)));
typedef float    v4f   __attribute__((ext_vector_type(4)));

#define T_LEN 512
#define KS 72   // fp16 row stride of h planes (16B-aligned b128 reads)

static __device__ __forceinline__ v4f mfma16(half8 a, half8 b, v4f c) {
    return __builtin_amdgcn_mfma_f32_16x16x32_f16(a, b, c, 0, 0, 0);
}
static __device__ __forceinline__ half8 ld8(const _Float16* p) {
    return *(const half8*)p;
}
// full-rate 2^s: round-to-nearest split + degree-5 Taylor (coeffs ln2^k/k!),
// |f|<=0.5 -> rel err ~2.5e-6; scale via v_ldexp_f32. ~9 VALU instr, 0 trans.
static __device__ __forceinline__ float exp2_fast(float s) {
    const float k = rintf(s);                  // v_rndne_f32
    const float f = s - k;
    float p = fmaf(f, 0.0013333558f, 0.0096181291f);
    p = fmaf(f, p, 0.0555041087f);
    p = fmaf(f, p, 0.2402265070f);
    p = fmaf(f, p, 0.6931471806f);
    p = fmaf(f, p, 1.0f);
    return __builtin_amdgcn_ldexpf(p, (int)k); // v_ldexp_f32 (full rate)
}
// full-rate reciprocal: magic seed + 2 Newton (rel err ~6e-6)
static __device__ __forceinline__ float rcp_fast(float d) {
    float y = __builtin_bit_cast(float, 0x7EF127EAu - __builtin_bit_cast(unsigned, d));
    y = y * (2.0f - d * y);
    y = y * (2.0f - d * y);
    return y;
}
#define NLOG2E  (-1.4426950408889634f)   // -log2(e)
#define N2LOG2E (-2.8853900817779268f)   // -2*log2(e)
// merged GRU cell, zero-trans: r=sigm(ar), z=sigm(az), n=tanh(ni+r*nh),
// h' = n + z*(h-n) = [A(1-B) + h(1+B)] / [(1+A)(1+B)]
static __device__ __forceinline__ float gru_cell(float ar, float az,
                                                 float ni, float nh, float h) {
    const float C  = exp2_fast(ar * NLOG2E);
    const float r  = rcp_fast(1.0f + C);
    const float w  = fmaf(r, nh, ni);
    const float A  = exp2_fast(az * NLOG2E);
    const float Bv = exp2_fast(w * N2LOG2E);
    const float num = fmaf(h, 1.0f + Bv, A * (1.0f - Bv));
    const float den = (1.0f + A) * (1.0f + Bv);
    return num * rcp_fast(den);
}

__global__ __launch_bounds__(512, 1)
void gru_mfma(const float* __restrict__ x,
              const float* __restrict__ w_ih0, const float* __restrict__ w_hh0,
              const float* __restrict__ b_ih0, const float* __restrict__ b_hh0,
              const float* __restrict__ w_ih1, const float* __restrict__ w_hh1,
              const float* __restrict__ b_ih1, const float* __restrict__ b_hh1,
              const float* __restrict__ fc_w,  const float* __restrict__ fc_b,
              float* __restrict__ out)
{
    __shared__ __align__(16) float xs[T_LEN * 16];        // [t][m], 32 KB
    __shared__ __align__(16) _Float16 h0f[2][16 * KS];    // h0 fp16, 2 parities
    __shared__ __align__(16) _Float16 h1f[2][16 * KS];    // h1 fp16, 2 parities
    __shared__ float red[64];

    const int tid  = threadIdx.x;
    const int wv   = tid >> 6;
    const int grp  = wv >> 2;       // 0 = layer-0 group, 1 = layer-1 group
    const int w    = wv & 3;        // N-split within group
    const int lane = tid & 63;
    const int n    = lane & 15;
    const int q    = lane >> 4;
    const int u    = w * 16 + n;    // unit owned in gate phase

    // ---- stage this block's 16 x-rows into LDS as [t][m] (coalesced) ----
    const float* xg = x + (size_t)(blockIdx.x * 16) * T_LEN;
    for (int i = tid; i < 16 * T_LEN; i += 512) {
        const int row = i >> 9, t = i & 511;
        xs[t * 16 + row] = xg[row * T_LEN + t];
    }
    // zero parity-1 buffers (read before first write)
    for (int i = tid; i < 16 * KS; i += 512) {
        h0f[1][i] = (_Float16)0;
        h1f[1][i] = (_Float16)0;
    }

    // ---- loop-invariant weight B-fragments (single fp16), group-specific ----
    // grp0 uses c=0,1 (W_hh0, K=64); grp1 uses c=0..3 ([W_ih1 | W_hh1], K=128)
    half8 B[3][4];
    {
        const int rows[3] = {u, 64 + u, 128 + u};
        const float* bc[4];
        if (grp == 0) {
            bc[0] = w_hh0;      bc[1] = w_hh0 + 32;
            bc[2] = w_hh0;      bc[3] = w_hh0 + 32;   // unused dups
        } else {
            bc[0] = w_ih1;      bc[1] = w_ih1 + 32;
            bc[2] = w_hh1;      bc[3] = w_hh1 + 32;
        }
        #pragma unroll
        for (int g = 0; g < 3; g++)
            #pragma unroll
            for (int c = 0; c < 4; c++) {
                const float* r0 = bc[c] + rows[g] * 64 + 8 * q;
                #pragma unroll
                for (int j = 0; j < 8; j++) B[g][c][j] = (_Float16)r0[j];
            }
    }

    // per-lane gate constants for unit u (group-specific)
    float wir = 0.f, wiz = 0.f, win = 0.f, brc = 0.f, bzc = 0.f, binc = 0.f, bhnc = 0.f;
    if (grp == 0) {
        wir = w_ih0[u]; wiz = w_ih0[64 + u]; win = w_ih0[128 + u];
        brc = b_ih0[u] + b_hh0[u];
        bzc = b_ih0[64 + u] + b_hh0[64 + u];
        binc = b_ih0[128 + u]; bhnc = b_hh0[128 + u];
    } else {
        brc = b_ih1[u] + b_hh1[u];
        bzc = b_ih1[64 + u] + b_hh1[64 + u];
        binc = b_ih1[128 + u]; bhnc = b_hh1[128 + u];
    }

    float hst[4] = {0.f, 0.f, 0.f, 0.f};   // fp32 h[m=4q+reg][u] (own layer)

    __syncthreads();

    const int abase = n * KS + 8 * q;       // A-frag base (fp16 elems)

    #pragma unroll 1
    for (int k = 0; k < T_LEN + 1; k++) {
        if (grp == 0) {
            if (k < T_LEN) {
                const int pw = k & 1, pr = pw ^ 1;
                // A-frags of h0(k-1) — written @k-1 pre-barrier, visible now
                const half8 a0 = ld8(&h0f[pr][abase]);
                const half8 a1 = ld8(&h0f[pr][abase + 32]);
                const v4f xv = *(const v4f*)(xs + k * 16 + 4 * q);  // broadcast

                v4f accR, accZ, accN;
                #pragma unroll
                for (int r = 0; r < 4; r++) {
                    accR[r] = fmaf(xv[r], wir, brc);
                    accZ[r] = fmaf(xv[r], wiz, bzc);
                    accN[r] = 0.f;
                }
                accR = mfma16(a0, B[0][0], accR);
                accZ = mfma16(a0, B[1][0], accZ);
                accN = mfma16(a0, B[2][0], accN);
                accR = mfma16(a1, B[0][1], accR);
                accZ = mfma16(a1, B[1][1], accZ);
                accN = mfma16(a1, B[2][1], accN);

                #pragma unroll
                for (int r = 0; r < 4; r++) {
                    const float inn = fmaf(xv[r], win, binc);
                    const float h = gru_cell(accR[r], accZ[r],
                                             inn, accN[r] + bhnc, hst[r]);
                    hst[r] = h;
                    h0f[pw][(4 * q + r) * KS + u] = (_Float16)h;
                }
            }
        } else {
            if (k > 0) {
                const int t = k - 1;
                const int pw = t & 1;       // h0(t) parity; h1(t) write parity
                const int p1 = pw ^ 1;      // h1(t-1) parity
                const half8 g00 = ld8(&h0f[pw][abase]);        // h0new(t)
                const half8 g01 = ld8(&h0f[pw][abase + 32]);
                const half8 g10 = ld8(&h1f[p1][abase]);        // h1(t-1)
                const half8 g11 = ld8(&h1f[p1][abase + 32]);

                v4f aR, aZ, aNi, aNh;
                #pragma unroll
                for (int r = 0; r < 4; r++) {
                    aR[r] = brc;  aZ[r] = bzc;  aNi[r] = binc;  aNh[r] = bhnc;
                }
                // r,z fold i-side and h-side into one acc; n keeps them apart
                aR  = mfma16(g00, B[0][0], aR);
                aZ  = mfma16(g00, B[1][0], aZ);
                aNi = mfma16(g00, B[2][0], aNi);
                aNh = mfma16(g10, B[2][2], aNh);
                aR  = mfma16(g01, B[0][1], aR);
                aZ  = mfma16(g01, B[1][1], aZ);
                aNi = mfma16(g01, B[2][1], aNi);
                aNh = mfma16(g11, B[2][3], aNh);
                aR  = mfma16(g10, B[0][2], aR);
                aZ  = mfma16(g10, B[1][2], aZ);
                aR  = mfma16(g11, B[0][3], aR);
                aZ  = mfma16(g11, B[1][3], aZ);

                #pragma unroll
                for (int r = 0; r < 4; r++) {
                    const float h = gru_cell(aR[r], aZ[r],
                                             aNi[r], aNh[r], hst[r]);
                    hst[r] = h;
                    h1f[pw][(4 * q + r) * KS + u] = (_Float16)h;
                }
            }
        }
        __syncthreads();   // the ONE barrier per window (anti-dependence)
    }

    // ======== FC epilogue: out[m] = sum_u fc_w[u] h1[m][u] + fc_b ========
    if (grp == 1) {
        const float fw = fc_w[u];
        #pragma unroll
        for (int r = 0; r < 4; r++) {
            float v = fw * hst[r];
            v += __shfl_xor(v, 1, 64);
            v += __shfl_xor(v, 2, 64);
            v += __shfl_xor(v, 4, 64);
            v += __shfl_xor(v, 8, 64);   // sum over 16 n-lanes (q preserved)
            if (n == 0) red[(4 * q + r) * 4 + w] = v;
        }
    }
    __syncthreads();
    if (tid < 16) {
        const float s = red[tid * 4] + red[tid * 4 + 1] + red[tid * 4 + 2] + red[tid * 4 + 3];
        out[blockIdx.x * 16 + tid] = s + fc_b[0];
    }
}

extern "C" void kernel_launch(void* const* d_in, const int* in_sizes, int n_in,
                              void* d_out, int out_size, void* d_ws, size_t ws_size,
                              hipStream_t stream)
{
    const float* x     = (const float*)d_in[0];
    const float* w_ih0 = (const float*)d_in[1];
    const float* w_hh0 = (const float*)d_in[2];
    const float* b_ih0 = (const float*)d_in[3];
    const float* b_hh0 = (const float*)d_in[4];
    const float* w_ih1 = (const float*)d_in[5];
    const float* w_hh1 = (const float*)d_in[6];
    const float* b_ih1 = (const float*)d_in[7];
    const float* b_hh1 = (const float*)d_in[8];
    const float* fc_w  = (const float*)d_in[9];
    const float* fc_b  = (const float*)d_in[10];
    float* out = (float*)d_out;

    hipLaunchKernelGGL(gru_mfma, dim3(256), dim3(512), 0, stream,
                       x, w_ih0, w_hh0, b_ih0, b_hh0,
                       w_ih1, w_hh1, b_ih1, b_hh1, fc_w, fc_b, out);
}

// Round 13
// 475.764 us; speedup vs baseline: 1.0952x; 1.0952x over previous
//
#include <hip/hip_runtime.h>

// GRUModel: 2-layer GRU (H=64), B=4096, T=512, fp32 in/out — MFMA round 13.
//
// R13 = R11 (470us champion) with ONE targeted change, informed by R12's
// falsification: software exp only pays OFF the dependency spine.
//   - merged cell spine C -> r -> w -> B stays on hardware __expf (short
//     latency, 2 trans instr/cell);
//   - A = e^-az (consumed only in the final num/den) moves to exp2_fast
//     (9 full-rate instr, chain ~36 cyc hides under the ~110-cyc spine);
//   - rcp_fast uses 2 Newton steps (R12 proved absmax-insensitive).
// Trans law (R8: 48 -> 2873; R11: 24 -> 2129; 32 cyc/trans/SIMD):
// 16 trans/SIMD -> window ~1920 -> ~410 us predicted.
//
// Structure (R8/R11): 256 blocks x 512 threads; waves 0-3 layer 0 @ window k,
// waves 4-7 layer 1 @ k-1; single fp16 MFMA operands; one barrier/window;
// parity double-buffered h planes; h-state fp32 in registers.
//
// Merged GRU cell (algebraically exact vs reference):
//   A=e^-az, B=e^-2w, C=e^-ar, w=ni+nh/(1+C),
//   h' = [A(1-B) + h(1+B)] / [(1+A)(1+B)]
//
// Frag layouts (m89/m120-verified):
//   A: lane holds A[m=lane&15][k=(lane>>4)*8+j], j=0..7
//   B: lane holds B[k=(lane>>4)*8+j][n=lane&15]
//   C/D: lane holds D[m=(lane>>4)*4+reg][n=lane&15]

typedef _Float16 half8 __attribute__((ext_vector_type(8)));
typedef float    v4f   __attribute__((ext_vector_type(4)));

#define T_LEN 512
#define KS 72   // fp16 row stride of h planes (16B-aligned b128 reads)

static __device__ __forceinline__ v4f mfma16(half8 a, half8 b, v4f c) {
    return __builtin_amdgcn_mfma_f32_16x16x32_f16(a, b, c, 0, 0, 0);
}
static __device__ __forceinline__ half8 ld8(const _Float16* p) {
    return *(const half8*)p;
}
// full-rate 2^s: rndne split + degree-5 Horner (ln2^k/k!), rel err ~2.5e-6
static __device__ __forceinline__ float exp2_fast(float s) {
    const float k = rintf(s);                  // v_rndne_f32
    const float f = s - k;
    float p = fmaf(f, 0.0013333558f, 0.0096181291f);
    p = fmaf(f, p, 0.0555041087f);
    p = fmaf(f, p, 0.2402265070f);
    p = fmaf(f, p, 0.6931471806f);
    p = fmaf(f, p, 1.0f);
    return __builtin_amdgcn_ldexpf(p, (int)k); // v_ldexp_f32 (full rate)
}
// full-rate reciprocal: magic seed + 2 Newton (rel err ~6e-6; R12-validated)
static __device__ __forceinline__ float rcp_fast(float d) {
    float y = __builtin_bit_cast(float, 0x7EF127EAu - __builtin_bit_cast(unsigned, d));
    y = y * (2.0f - d * y);
    y = y * (2.0f - d * y);
    return y;
}
#define NLOG2E (-1.4426950408889634f)   // -log2(e)
// merged GRU cell: spine C->r->w->B on hardware exp; off-spine A software
static __device__ __forceinline__ float gru_cell(float ar, float az,
                                                 float ni, float nh, float h) {
    const float C  = __expf(-ar);              // hw trans (spine)
    const float A  = exp2_fast(az * NLOG2E);   // software, off-spine
    const float r  = rcp_fast(1.0f + C);
    const float w  = fmaf(r, nh, ni);
    const float Bv = __expf(-2.0f * w);        // hw trans (spine)
    const float num = fmaf(h, 1.0f + Bv, A * (1.0f - Bv));
    const float den = (1.0f + A) * (1.0f + Bv);
    return num * rcp_fast(den);
}

__global__ __launch_bounds__(512, 1)
void gru_mfma(const float* __restrict__ x,
              const float* __restrict__ w_ih0, const float* __restrict__ w_hh0,
              const float* __restrict__ b_ih0, const float* __restrict__ b_hh0,
              const float* __restrict__ w_ih1, const float* __restrict__ w_hh1,
              const float* __restrict__ b_ih1, const float* __restrict__ b_hh1,
              const float* __restrict__ fc_w,  const float* __restrict__ fc_b,
              float* __restrict__ out)
{
    __shared__ __align__(16) float xs[T_LEN * 16];        // [t][m], 32 KB
    __shared__ __align__(16) _Float16 h0f[2][16 * KS];    // h0 fp16, 2 parities
    __shared__ __align__(16) _Float16 h1f[2][16 * KS];    // h1 fp16, 2 parities
    __shared__ float red[64];

    const int tid  = threadIdx.x;
    const int wv   = tid >> 6;
    const int grp  = wv >> 2;       // 0 = layer-0 group, 1 = layer-1 group
    const int w    = wv & 3;        // N-split within group
    const int lane = tid & 63;
    const int n    = lane & 15;
    const int q    = lane >> 4;
    const int u    = w * 16 + n;    // unit owned in gate phase

    // ---- stage this block's 16 x-rows into LDS as [t][m] (coalesced) ----
    const float* xg = x + (size_t)(blockIdx.x * 16) * T_LEN;
    for (int i = tid; i < 16 * T_LEN; i += 512) {
        const int row = i >> 9, t = i & 511;
        xs[t * 16 + row] = xg[row * T_LEN + t];
    }
    // zero parity-1 buffers (read before first write)
    for (int i = tid; i < 16 * KS; i += 512) {
        h0f[1][i] = (_Float16)0;
        h1f[1][i] = (_Float16)0;
    }

    // ---- loop-invariant weight B-fragments (single fp16), group-specific ----
    // grp0 uses c=0,1 (W_hh0, K=64); grp1 uses c=0..3 ([W_ih1 | W_hh1], K=128)
    half8 B[3][4];
    {
        const int rows[3] = {u, 64 + u, 128 + u};
        const float* bc[4];
        if (grp == 0) {
            bc[0] = w_hh0;      bc[1] = w_hh0 + 32;
            bc[2] = w_hh0;      bc[3] = w_hh0 + 32;   // unused dups
        } else {
            bc[0] = w_ih1;      bc[1] = w_ih1 + 32;
            bc[2] = w_hh1;      bc[3] = w_hh1 + 32;
        }
        #pragma unroll
        for (int g = 0; g < 3; g++)
            #pragma unroll
            for (int c = 0; c < 4; c++) {
                const float* r0 = bc[c] + rows[g] * 64 + 8 * q;
                #pragma unroll
                for (int j = 0; j < 8; j++) B[g][c][j] = (_Float16)r0[j];
            }
    }

    // per-lane gate constants for unit u (group-specific)
    float wir = 0.f, wiz = 0.f, win = 0.f, brc = 0.f, bzc = 0.f, binc = 0.f, bhnc = 0.f;
    if (grp == 0) {
        wir = w_ih0[u]; wiz = w_ih0[64 + u]; win = w_ih0[128 + u];
        brc = b_ih0[u] + b_hh0[u];
        bzc = b_ih0[64 + u] + b_hh0[64 + u];
        binc = b_ih0[128 + u]; bhnc = b_hh0[128 + u];
    } else {
        brc = b_ih1[u] + b_hh1[u];
        bzc = b_ih1[64 + u] + b_hh1[64 + u];
        binc = b_ih1[128 + u]; bhnc = b_hh1[128 + u];
    }

    float hst[4] = {0.f, 0.f, 0.f, 0.f};   // fp32 h[m=4q+reg][u] (own layer)

    __syncthreads();

    const int abase = n * KS + 8 * q;       // A-frag base (fp16 elems)

    #pragma unroll 1
    for (int k = 0; k < T_LEN + 1; k++) {
        if (grp == 0) {
            if (k < T_LEN) {
                const int pw = k & 1, pr = pw ^ 1;
                // A-frags of h0(k-1) — written @k-1 pre-barrier, visible now
                const half8 a0 = ld8(&h0f[pr][abase]);
                const half8 a1 = ld8(&h0f[pr][abase + 32]);
                const v4f xv = *(const v4f*)(xs + k * 16 + 4 * q);  // broadcast

                v4f accR, accZ, accN;
                #pragma unroll
                for (int r = 0; r < 4; r++) {
                    accR[r] = fmaf(xv[r], wir, brc);
                    accZ[r] = fmaf(xv[r], wiz, bzc);
                    accN[r] = 0.f;
                }
                accR = mfma16(a0, B[0][0], accR);
                accZ = mfma16(a0, B[1][0], accZ);
                accN = mfma16(a0, B[2][0], accN);
                accR = mfma16(a1, B[0][1], accR);
                accZ = mfma16(a1, B[1][1], accZ);
                accN = mfma16(a1, B[2][1], accN);

                #pragma unroll
                for (int r = 0; r < 4; r++) {
                    const float inn = fmaf(xv[r], win, binc);
                    const float h = gru_cell(accR[r], accZ[r],
                                             inn, accN[r] + bhnc, hst[r]);
                    hst[r] = h;
                    h0f[pw][(4 * q + r) * KS + u] = (_Float16)h;
                }
            }
        } else {
            if (k > 0) {
                const int t = k - 1;
                const int pw = t & 1;       // h0(t) parity; h1(t) write parity
                const int p1 = pw ^ 1;      // h1(t-1) parity
                const half8 g00 = ld8(&h0f[pw][abase]);        // h0new(t)
                const half8 g01 = ld8(&h0f[pw][abase + 32]);
                const half8 g10 = ld8(&h1f[p1][abase]);        // h1(t-1)
                const half8 g11 = ld8(&h1f[p1][abase + 32]);

                v4f aR, aZ, aNi, aNh;
                #pragma unroll
                for (int r = 0; r < 4; r++) {
                    aR[r] = brc;  aZ[r] = bzc;  aNi[r] = binc;  aNh[r] = bhnc;
                }
                // r,z fold i-side and h-side into one acc; n keeps them apart
                aR  = mfma16(g00, B[0][0], aR);
                aZ  = mfma16(g00, B[1][0], aZ);
                aNi = mfma16(g00, B[2][0], aNi);
                aNh = mfma16(g10, B[2][2], aNh);
                aR  = mfma16(g01, B[0][1], aR);
                aZ  = mfma16(g01, B[1][1], aZ);
                aNi = mfma16(g01, B[2][1], aNi);
                aNh = mfma16(g11, B[2][3], aNh);
                aR  = mfma16(g10, B[0][2], aR);
                aZ  = mfma16(g10, B[1][2], aZ);
                aR  = mfma16(g11, B[0][3], aR);
                aZ  = mfma16(g11, B[1][3], aZ);

                #pragma unroll
                for (int r = 0; r < 4; r++) {
                    const float h = gru_cell(aR[r], aZ[r],
                                             aNi[r], aNh[r], hst[r]);
                    hst[r] = h;
                    h1f[pw][(4 * q + r) * KS + u] = (_Float16)h;
                }
            }
        }
        __syncthreads();   // the ONE barrier per window (anti-dependence)
    }

    // ======== FC epilogue: out[m] = sum_u fc_w[u] h1[m][u] + fc_b ========
    if (grp == 1) {
        const float fw = fc_w[u];
        #pragma unroll
        for (int r = 0; r < 4; r++) {
            float v = fw * hst[r];
            v += __shfl_xor(v, 1, 64);
            v += __shfl_xor(v, 2, 64);
            v += __shfl_xor(v, 4, 64);
            v += __shfl_xor(v, 8, 64);   // sum over 16 n-lanes (q preserved)
            if (n == 0) red[(4 * q + r) * 4 + w] = v;
        }
    }
    __syncthreads();
    if (tid < 16) {
        const float s = red[tid * 4] + red[tid * 4 + 1] + red[tid * 4 + 2] + red[tid * 4 + 3];
        out[blockIdx.x * 16 + tid] = s + fc_b[0];
    }
}

extern "C" void kernel_launch(void* const* d_in, const int* in_sizes, int n_in,
                              void* d_out, int out_size, void* d_ws, size_t ws_size,
                              hipStream_t stream)
{
    const float* x     = (const float*)d_in[0];
    const float* w_ih0 = (const float*)d_in[1];
    const float* w_hh0 = (const float*)d_in[2];
    const float* b_ih0 = (const float*)d_in[3];
    const float* b_hh0 = (const float*)d_in[4];
    const float* w_ih1 = (const float*)d_in[5];
    const float* w_hh1 = (const float*)d_in[6];
    const float* b_ih1 = (const float*)d_in[7];
    const float* b_hh1 = (const float*)d_in[8];
    const float* fc_w  = (const float*)d_in[9];
    const float* fc_b  = (const float*)d_in[10];
    float* out = (float*)d_out;

    hipLaunchKernelGGL(gru_mfma, dim3(256), dim3(512), 0, stream,
                       x, w_ih0, w_hh0, b_ih0, b_hh0,
                       w_ih1, w_hh1, b_ih1, b_hh1, fc_w, fc_b, out);
}